// Round 1
// baseline (1277.819 us; speedup 1.0000x reference)
//
#include <hip/hip_runtime.h>

#define N_NODES   1000000
#define N_EDGES   2000000
#define N_FEAT    11
#define HIDDEN    64
#define BATCH     128
#define N_CLASSES 19

// ---------------- kernel 1: in-degree over targets ----------------
__global__ void deg_kernel(const int* __restrict__ col, float* __restrict__ deg) {
    int e = blockIdx.x * blockDim.x + threadIdx.x;
    if (e < N_EDGES) atomicAdd(&deg[col[e]], 1.0f);
}

// ---------------- kernel 2: deg -> dinv (in place) ----------------
__global__ void dinv_kernel(float* __restrict__ deg) {
    int n = blockIdx.x * blockDim.x + threadIdx.x;
    if (n < N_NODES) {
        float d = deg[n];
        deg[n] = (d > 0.0f) ? rsqrtf(d) : 0.0f;
    }
}

// ---------------- kernel 3: scatter raw 11-dim features ----------------
// agg[c,:] += dinv[r]*dinv[c] * x[r,:]   (aggregation commutes with the
// linear transform, so we aggregate BEFORE applying W_conv: 11 floats/edge
// instead of 64)
__global__ void scatter_kernel(const int* __restrict__ row, const int* __restrict__ col,
                               const float* __restrict__ x, const float* __restrict__ dinv,
                               float* __restrict__ agg) {
    int e = blockIdx.x * blockDim.x + threadIdx.x;
    if (e >= N_EDGES) return;
    int r = row[e];
    int c = col[e];
    float norm = dinv[r] * dinv[c];
    if (norm == 0.0f) return;  // r has zero in-degree -> message is exactly 0
    const float* xr = x   + (size_t)r * N_FEAT;
    float*       ag = agg + (size_t)c * N_FEAT;
#pragma unroll
    for (int k = 0; k < N_FEAT; ++k)
        atomicAdd(&ag[k], norm * xr[k]);
}

// ---------------- kernel 4: per-node transform+relu, fused mean-pool ----
// one wave per chunk of nodes; lane j owns hidden channel j.
// batch ids are sorted, so a chunk spans 1-2 segments -> ~2 flushes/block.
__global__ __launch_bounds__(64) void node_pool_kernel(
    const float* __restrict__ agg, const int* __restrict__ batch,
    const float* __restrict__ Wc, const float* __restrict__ bc,
    float* __restrict__ pooled, float* __restrict__ counts) {
    const int lane = threadIdx.x;  // 0..63
    float w[N_FEAT];
#pragma unroll
    for (int k = 0; k < N_FEAT; ++k) w[k] = Wc[k * HIDDEN + lane];  // coalesced
    const float bias = bc[lane];

    const long nblocks = gridDim.x;
    const long per     = (N_NODES + nblocks - 1) / nblocks;
    const long start   = (long)blockIdx.x * per;
    const long end     = (start + per < N_NODES) ? (start + per) : N_NODES;
    if (start >= end) return;

    int   cur = batch[start];
    float acc = 0.0f;
    float cnt = 0.0f;
    for (long n = start; n < end; ++n) {
        int bid = batch[n];  // same addr across lanes -> broadcast
        if (bid != cur) {
            atomicAdd(&pooled[(size_t)cur * HIDDEN + lane], acc);
            if (lane == 0) atomicAdd(&counts[cur], cnt);
            acc = 0.0f; cnt = 0.0f; cur = bid;
        }
        const float* a = agg + (size_t)n * N_FEAT;
        float h = bias;
#pragma unroll
        for (int k = 0; k < N_FEAT; ++k) h = fmaf(a[k], w[k], h);
        acc += fmaxf(h, 0.0f);
        cnt += 1.0f;
    }
    atomicAdd(&pooled[(size_t)cur * HIDDEN + lane], acc);
    if (lane == 0) atomicAdd(&counts[cur], cnt);
}

// ---------------- kernel 5: epilogue  out = (pooled/cnt) @ W_lin + b_lin ----
__global__ void final_kernel(const float* __restrict__ pooled, const float* __restrict__ counts,
                             const float* __restrict__ Wl, const float* __restrict__ bl,
                             float* __restrict__ out) {
    int i = blockIdx.x * blockDim.x + threadIdx.x;
    if (i >= BATCH * N_CLASSES) return;
    int b = i / N_CLASSES;
    int c = i - b * N_CLASSES;
    float inv = 1.0f / fmaxf(counts[b], 1.0f);
    float s = bl[c];
#pragma unroll 8
    for (int h = 0; h < HIDDEN; ++h)
        s = fmaf(pooled[b * HIDDEN + h] * inv, Wl[h * N_CLASSES + c], s);
    out[i] = s;
}

extern "C" void kernel_launch(void* const* d_in, const int* in_sizes, int n_in,
                              void* d_out, int out_size, void* d_ws, size_t ws_size,
                              hipStream_t stream) {
    // setup_inputs order: x, edge_index, y(unused), batch, W_conv, b_conv, W_lin, b_lin
    const float* x     = (const float*)d_in[0];
    const int*   ei    = (const int*)d_in[1];   // [2, E] row-major, int32 (jax x64 off)
    const int*   batch = (const int*)d_in[3];
    const float* Wc    = (const float*)d_in[4];
    const float* bc    = (const float*)d_in[5];
    const float* Wl    = (const float*)d_in[6];
    const float* bl    = (const float*)d_in[7];
    float*       out   = (float*)d_out;

    // workspace layout (floats): deg/dinv [N], agg [N*11], pooled [128*64], counts [128]
    float* deg    = (float*)d_ws;
    float* agg    = deg + N_NODES;
    float* pooled = agg + (size_t)N_NODES * N_FEAT;
    float* counts = pooled + BATCH * HIDDEN;
    size_t zero_bytes = ((size_t)N_NODES + (size_t)N_NODES * N_FEAT
                         + BATCH * HIDDEN + BATCH) * sizeof(float);  // ~48 MB
    hipMemsetAsync(d_ws, 0, zero_bytes, stream);

    const int* row = ei;
    const int* col = ei + N_EDGES;

    deg_kernel <<<(N_EDGES + 255) / 256, 256, 0, stream>>>(col, deg);
    dinv_kernel<<<(N_NODES + 255) / 256, 256, 0, stream>>>(deg);
    scatter_kernel<<<(N_EDGES + 255) / 256, 256, 0, stream>>>(row, col, x, deg, agg);
    node_pool_kernel<<<4096, 64, 0, stream>>>(agg, batch, Wc, bc, pooled, counts);
    final_kernel<<<(BATCH * N_CLASSES + 255) / 256, 256, 0, stream>>>(pooled, counts, Wl, bl, out);
}

// Round 2
// 517.644 us; speedup vs baseline: 2.4685x; 2.4685x over previous
//
#include <hip/hip_runtime.h>

#define N_NODES   1000000
#define N_EDGES   2000000
#define N_FEAT    11
#define HIDDEN    64
#define BATCH     128
#define N_CLASSES 19

// scan geometry: 256 threads x 16 items = 4096 nodes per block
#define SCAN_T    256
#define SCAN_I    16
#define SCAN_TILE (SCAN_T * SCAN_I)
#define NBLK      ((N_NODES + SCAN_TILE - 1) / SCAN_TILE)   // 245

// ---------------- kernel 1: int in-degree histogram over targets ----------
__global__ void deg_kernel(const int* __restrict__ col, int* __restrict__ deg) {
    int e = blockIdx.x * blockDim.x + threadIdx.x;
    if (e < N_EDGES) atomicAdd(&deg[col[e]], 1);
}

// ---------------- scan A: per-block sums ----------------------------------
__global__ __launch_bounds__(SCAN_T) void scanA_kernel(const int* __restrict__ deg,
                                                       int* __restrict__ bsum) {
    __shared__ int sh[SCAN_T];
    int base = blockIdx.x * SCAN_TILE + threadIdx.x * SCAN_I;
    int s = 0;
#pragma unroll
    for (int j = 0; j < SCAN_I; ++j) {
        int n = base + j;
        if (n < N_NODES) s += deg[n];
    }
    sh[threadIdx.x] = s;
    __syncthreads();
    for (int off = SCAN_T / 2; off > 0; off >>= 1) {
        if (threadIdx.x < off) sh[threadIdx.x] += sh[threadIdx.x + off];
        __syncthreads();
    }
    if (threadIdx.x == 0) bsum[blockIdx.x] = sh[0];
}

// ---------------- scan B: scan the 245 block sums (single thread) ---------
__global__ void scanB_kernel(int* __restrict__ bsum) {
    int running = 0;
    for (int i = 0; i < NBLK; ++i) {
        int v = bsum[i];
        bsum[i] = running;
        running += v;
    }
}

// ---------------- scan C: write exclusive prefix into cursor --------------
__global__ __launch_bounds__(SCAN_T) void scanC_kernel(const int* __restrict__ deg,
                                                       const int* __restrict__ bsum,
                                                       int* __restrict__ cursor) {
    __shared__ int sh[SCAN_T];
    const int tid = threadIdx.x;
    int base = blockIdx.x * SCAN_TILE + tid * SCAN_I;
    int loc[SCAN_I];
    int s = 0;
#pragma unroll
    for (int j = 0; j < SCAN_I; ++j) {
        int n = base + j;
        loc[j] = s;
        if (n < N_NODES) s += deg[n];
    }
    sh[tid] = s;
    __syncthreads();
    // Hillis-Steele inclusive scan over 256 thread sums
    for (int off = 1; off < SCAN_T; off <<= 1) {
        int v = (tid >= off) ? sh[tid - off] : 0;
        __syncthreads();
        sh[tid] += v;
        __syncthreads();
    }
    int tpre = bsum[blockIdx.x] + sh[tid] - s;  // exclusive prefix for this thread
#pragma unroll
    for (int j = 0; j < SCAN_I; ++j) {
        int n = base + j;
        if (n < N_NODES) cursor[n] = tpre + loc[j];
    }
}

// ---------------- fill: bucket source ids by target (CSR build) -----------
__global__ void fill_kernel(const int* __restrict__ row, const int* __restrict__ col,
                            int* __restrict__ cursor, int* __restrict__ srcs) {
    int e = blockIdx.x * blockDim.x + threadIdx.x;
    if (e >= N_EDGES) return;
    int pos = atomicAdd(&cursor[col[e]], 1);
    srcs[pos] = row[e];
}
// after fill: cursor[n] == end offset of node n's bucket; start = end - deg[n]

// ---------------- gather: agg[n,:] = dinv[n] * sum_r dinv[r]*x[r,:] -------
__global__ void gather_kernel(const int* __restrict__ deg, const int* __restrict__ cursor,
                              const int* __restrict__ srcs, const float* __restrict__ x,
                              float* __restrict__ agg) {
    int n = blockIdx.x * blockDim.x + threadIdx.x;
    if (n >= N_NODES) return;
    int d   = deg[n];
    int end = cursor[n];
    float acc[N_FEAT];
#pragma unroll
    for (int k = 0; k < N_FEAT; ++k) acc[k] = 0.0f;
    for (int i = end - d; i < end; ++i) {
        int r  = srcs[i];
        int dr = deg[r];
        if (dr == 0) continue;                 // dinv[r] == 0 -> zero message
        float nr = rsqrtf((float)dr);
        const float* xr = x + (size_t)r * N_FEAT;
#pragma unroll
        for (int k = 0; k < N_FEAT; ++k) acc[k] = fmaf(nr, xr[k], acc[k]);
    }
    float dc = (d > 0) ? rsqrtf((float)d) : 0.0f;
    float* ag = agg + (size_t)n * N_FEAT;
#pragma unroll
    for (int k = 0; k < N_FEAT; ++k) ag[k] = dc * acc[k];
}

// ---------------- node transform + relu + fused mean-pool -----------------
__global__ __launch_bounds__(64) void node_pool_kernel(
    const float* __restrict__ agg, const int* __restrict__ batch,
    const float* __restrict__ Wc, const float* __restrict__ bc,
    float* __restrict__ pooled, float* __restrict__ counts) {
    const int lane = threadIdx.x;  // 0..63, owns hidden channel `lane`
    float w[N_FEAT];
#pragma unroll
    for (int k = 0; k < N_FEAT; ++k) w[k] = Wc[k * HIDDEN + lane];
    const float bias = bc[lane];

    const long nblocks = gridDim.x;
    const long per     = (N_NODES + nblocks - 1) / nblocks;
    const long start   = (long)blockIdx.x * per;
    const long end     = (start + per < N_NODES) ? (start + per) : N_NODES;
    if (start >= end) return;

    int   cur = batch[start];
    float acc = 0.0f;
    float cnt = 0.0f;
    for (long n = start; n < end; ++n) {
        int bid = batch[n];
        if (bid != cur) {
            atomicAdd(&pooled[(size_t)cur * HIDDEN + lane], acc);
            if (lane == 0) atomicAdd(&counts[cur], cnt);
            acc = 0.0f; cnt = 0.0f; cur = bid;
        }
        const float* a = agg + (size_t)n * N_FEAT;
        float h = bias;
#pragma unroll
        for (int k = 0; k < N_FEAT; ++k) h = fmaf(a[k], w[k], h);
        acc += fmaxf(h, 0.0f);
        cnt += 1.0f;
    }
    atomicAdd(&pooled[(size_t)cur * HIDDEN + lane], acc);
    if (lane == 0) atomicAdd(&counts[cur], cnt);
}

// ---------------- epilogue: out = (pooled/cnt) @ W_lin + b_lin ------------
__global__ void final_kernel(const float* __restrict__ pooled, const float* __restrict__ counts,
                             const float* __restrict__ Wl, const float* __restrict__ bl,
                             float* __restrict__ out) {
    int i = blockIdx.x * blockDim.x + threadIdx.x;
    if (i >= BATCH * N_CLASSES) return;
    int b = i / N_CLASSES;
    int c = i - b * N_CLASSES;
    float inv = 1.0f / fmaxf(counts[b], 1.0f);
    float s = bl[c];
#pragma unroll 8
    for (int h = 0; h < HIDDEN; ++h)
        s = fmaf(pooled[b * HIDDEN + h] * inv, Wl[h * N_CLASSES + c], s);
    out[i] = s;
}

extern "C" void kernel_launch(void* const* d_in, const int* in_sizes, int n_in,
                              void* d_out, int out_size, void* d_ws, size_t ws_size,
                              hipStream_t stream) {
    // setup_inputs order: x, edge_index, y(unused), batch, W_conv, b_conv, W_lin, b_lin
    const float* x     = (const float*)d_in[0];
    const int*   ei    = (const int*)d_in[1];   // [2, E] row-major int32
    const int*   batch = (const int*)d_in[3];
    const float* Wc    = (const float*)d_in[4];
    const float* bc    = (const float*)d_in[5];
    const float* Wl    = (const float*)d_in[6];
    const float* bl    = (const float*)d_in[7];
    float*       out   = (float*)d_out;

    // ws layout: [deg N int][pooled 8192 f][counts 128 f][cursor N int]
    //            [srcs E int][agg N*11 f][bsum 256 int]   (~60 MB)
    int*   deg    = (int*)d_ws;
    float* pooled = (float*)(deg + N_NODES);
    float* counts = pooled + BATCH * HIDDEN;
    int*   cursor = (int*)(counts + BATCH);
    int*   srcs   = cursor + N_NODES;
    float* agg    = (float*)(srcs + N_EDGES);
    int*   bsum   = (int*)(agg + (size_t)N_NODES * N_FEAT);

    // zero only deg + pooled + counts (contiguous prefix)
    size_t zero_bytes = ((size_t)N_NODES + BATCH * HIDDEN + BATCH) * 4;
    hipMemsetAsync(d_ws, 0, zero_bytes, stream);

    const int* row = ei;
    const int* col = ei + N_EDGES;

    deg_kernel  <<<(N_EDGES + 255) / 256, 256, 0, stream>>>(col, deg);
    scanA_kernel<<<NBLK, SCAN_T, 0, stream>>>(deg, bsum);
    scanB_kernel<<<1, 1, 0, stream>>>(bsum);
    scanC_kernel<<<NBLK, SCAN_T, 0, stream>>>(deg, bsum, cursor);
    fill_kernel <<<(N_EDGES + 255) / 256, 256, 0, stream>>>(row, col, cursor, srcs);
    gather_kernel<<<(N_NODES + 255) / 256, 256, 0, stream>>>(deg, cursor, srcs, x, agg);
    node_pool_kernel<<<4096, 64, 0, stream>>>(agg, batch, Wc, bc, pooled, counts);
    final_kernel<<<(BATCH * N_CLASSES + 255) / 256, 256, 0, stream>>>(pooled, counts, Wl, bl, out);
}